// Round 6
// baseline (294.860 us; speedup 1.0000x reference)
//
#include <hip/hip_runtime.h>
#include <math.h>

typedef __attribute__((ext_vector_type(8))) short bf16x8;
typedef __attribute__((ext_vector_type(8))) unsigned short u16x8;
typedef __attribute__((ext_vector_type(4))) unsigned short u16x4;
typedef __attribute__((ext_vector_type(4))) float f32x4;
typedef unsigned short u16;

__device__ __forceinline__ u16 f2bf(float f) {
  unsigned u = __builtin_bit_cast(unsigned, f);
  return (u16)((u + 0x7FFFu + ((u >> 16) & 1u)) >> 16);
}

__device__ __forceinline__ void gload16(const u16* g, u16* l) {
  __builtin_amdgcn_global_load_lds((const __attribute__((address_space(1))) void*)g,
                                   (__attribute__((address_space(3))) void*)l, 16, 0, 0);
}

__device__ __forceinline__ void sbar() {
  __builtin_amdgcn_sched_barrier(0);
  __builtin_amdgcn_s_barrier();
  __builtin_amdgcn_sched_barrier(0);
}

#define VMWAIT(n) asm volatile("s_waitcnt vmcnt(" #n ")" ::: "memory")
#define MFMA16(a, b, c) __builtin_amdgcn_mfma_f32_16x16x32_bf16((a), (b), (c), 0, 0, 0)

__device__ __forceinline__ float decay_of(float d) {
  return 1e-12f + 0.5f + 0.5f / (1.0f + expf(-d));
}

// ---------------- prep: 3x f32 -> bf16 (w1, w2, audio fused) ----------------
__global__ __launch_bounds__(256) void cvt3_kernel(const float* __restrict__ a,
                                                   const float* __restrict__ b,
                                                   const float* __restrict__ c,
                                                   u16* __restrict__ out) {
  const int i = blockIdx.x * 256 + threadIdx.x;   // i < 3 * 1048576 (float4 units)
  const float* src;
  int j = i;
  if (i < 1048576) { src = a; }
  else if (i < 2097152) { src = b; j = i - 1048576; }
  else { src = c; j = i - 2097152; }
  const float4 v = ((const float4*)src)[j];
  u16x4 o = { f2bf(v.x), f2bf(v.y), f2bf(v.z), f2bf(v.w) };
  ((u16x4*)out)[i] = o;
}

// ---------------- prep: relu(cp) transposed to [t][c] bf16 ----------------
__global__ __launch_bounds__(256) void relu_t_kernel(const float* __restrict__ cp,
                                                     u16* __restrict__ x0t) {
  const int cb = blockIdx.x & 31;
  const int tb = blockIdx.x >> 5;
  __shared__ __attribute__((aligned(16))) float tile[64][65];
  const int tid = threadIdx.x;
  const int r0 = tid >> 4, i4 = (tid & 15) * 4;
  #pragma unroll
  for (int rr = 0; rr < 64; rr += 16) {
    const float4 v = *(const float4*)(cp + (size_t)(cb * 64 + r0 + rr) * 4096 + tb * 64 + i4);
    tile[r0 + rr][i4 + 0] = fmaxf(v.x, 0.f);
    tile[r0 + rr][i4 + 1] = fmaxf(v.y, 0.f);
    tile[r0 + rr][i4 + 2] = fmaxf(v.z, 0.f);
    tile[r0 + rr][i4 + 3] = fmaxf(v.w, 0.f);
  }
  __syncthreads();
  #pragma unroll
  for (int it = 0; it < 2; ++it) {
    const int chunk = it * 256 + tid;
    const int i = chunk >> 3, rp = (chunk & 7) * 8;
    u16x8 o;
    #pragma unroll
    for (int q = 0; q < 8; ++q) o[q] = f2bf(tile[rp + q][i]);
    *(u16x8*)(x0t + (size_t)(tb * 64 + i) * 2048 + cb * 64 + rp) = o;
  }
}

// ---------------- IIR blocked scan ----------------
__global__ __launch_bounds__(128) void iir_partial_kernel(const float* __restrict__ x,
                                                          const float* __restrict__ decays,
                                                          float* __restrict__ L) {
  const int tid = threadIdx.x;
  const int cb = blockIdx.x & 15;
  const int ck = blockIdx.x >> 4;
  const int c0 = cb * 128, t0 = ck * 64;
  __shared__ __attribute__((aligned(16))) float xs[128][65];
  const float dd = decay_of(decays[c0 + tid]);
  #pragma unroll
  for (int it = 0; it < 16; ++it) {
    const int idx = it * 128 + tid;
    const int r = idx >> 4, iv = (idx & 15) * 4;
    const float4 v = *(const float4*)(x + (size_t)(c0 + r) * 4096 + t0 + iv);
    xs[r][iv + 0] = v.x; xs[r][iv + 1] = v.y; xs[r][iv + 2] = v.z; xs[r][iv + 3] = v.w;
  }
  __syncthreads();
  float yv = 0.0f;
  #pragma unroll
  for (int i = 0; i < 64; ++i) yv = dd * (xs[tid][i] + yv);
  L[ck * 2048 + c0 + tid] = yv;
}

__global__ __launch_bounds__(128) void iir_carry_kernel(const float* __restrict__ L,
                                                        const float* __restrict__ decays,
                                                        float* __restrict__ Cin) {
  const int c = blockIdx.x * 128 + threadIdx.x;
  const float dd = decay_of(decays[c]);
  float A = dd;
  #pragma unroll
  for (int p = 0; p < 6; ++p) A = A * A;   // dd^64
  float carry = 0.0f;
  for (int j = 0; j < 64; ++j) {
    Cin[j * 2048 + c] = carry;
    carry = L[j * 2048 + c] + A * carry;
  }
}

__global__ __launch_bounds__(128) void iir_apply_kernel(const float* __restrict__ x,
                                                        const float* __restrict__ decays,
                                                        const float* __restrict__ Cin,
                                                        u16* __restrict__ yT) {
  const int tid = threadIdx.x;
  const int cb = blockIdx.x & 15;
  const int ck = blockIdx.x >> 4;
  const int c0 = cb * 128, t0 = ck * 64;
  __shared__ __attribute__((aligned(16))) float xs[128][65];
  __shared__ __attribute__((aligned(16))) u16 ys[64][136];
  const float dd = decay_of(decays[c0 + tid]);
  const float carry = Cin[ck * 2048 + c0 + tid];
  #pragma unroll
  for (int it = 0; it < 16; ++it) {
    const int idx = it * 128 + tid;
    const int r = idx >> 4, iv = (idx & 15) * 4;
    const float4 v = *(const float4*)(x + (size_t)(c0 + r) * 4096 + t0 + iv);
    xs[r][iv + 0] = v.x; xs[r][iv + 1] = v.y; xs[r][iv + 2] = v.z; xs[r][iv + 3] = v.w;
  }
  __syncthreads();
  float yv = carry;
  #pragma unroll
  for (int i = 0; i < 64; ++i) {
    yv = dd * (xs[tid][i] + yv);
    ys[i][tid] = f2bf(yv);
  }
  __syncthreads();
  #pragma unroll
  for (int it = 0; it < 8; ++it) {
    const int chunk = it * 128 + tid;
    const int i = chunk >> 4, cpv = (chunk & 15) * 8;
    u16x8 v = *(const u16x8*)&ys[i][cpv];
    *(u16x8*)(yT + (size_t)(t0 + i) * 2048 + c0 + cpv) = v;
  }
}

// ---------------- GEMM helpers ----------------
__device__ __forceinline__ void load_a(const u16* aBase, long koff, long K,
                                       bf16x8 (&a0)[4], bf16x8 (&a1)[4]) {
  #pragma unroll
  for (int mi = 0; mi < 4; ++mi) {
    a0[mi] = *(const bf16x8*)(aBase + (size_t)mi * 16 * K + koff);
    a1[mi] = *(const bf16x8*)(aBase + (size_t)mi * 16 * K + koff + 32);
  }
}

__device__ __forceinline__ void read_b(const u16* Bc, int rB0, int jk0, int jk1,
                                       bf16x8 (&b0)[4], bf16x8 (&b1)[4]) {
  #pragma unroll
  for (int ni = 0; ni < 4; ++ni)
    b0[ni] = *(const bf16x8*)(Bc + (rB0 + ni * 16) * 64 + jk0 * 8);
  #pragma unroll
  for (int ni = 0; ni < 4; ++ni)
    b1[ni] = *(const bf16x8*)(Bc + (rB0 + ni * 16) * 64 + jk1 * 8);
}

__device__ __forceinline__ void do_mfma(const bf16x8 (&a0)[4], const bf16x8 (&a1)[4],
                                        const bf16x8 (&b0)[4], const bf16x8 (&b1)[4],
                                        f32x4 (&acc)[4][4]) {
  __builtin_amdgcn_s_setprio(1);
  #pragma unroll
  for (int mi = 0; mi < 4; ++mi)
    #pragma unroll
    for (int ni = 0; ni < 4; ++ni)
      acc[mi][ni] = MFMA16(a0[mi], b0[ni], acc[mi][ni]);
  #pragma unroll
  for (int mi = 0; mi < 4; ++mi)
    #pragma unroll
    for (int ni = 0; ni < 4; ++ni)
      acc[mi][ni] = MFMA16(a1[mi], b1[ni], acc[mi][ni]);
  __builtin_amdgcn_s_setprio(0);
}

// ---------------- GEMM: 128x128 tile, BK=64; A direct global->reg, B LDS-dbuf ----------------
// C[M][N] = A[M][K] @ Bt[N][K]^T. 256 thr = 4 waves (2M x 2N), per-wave 64x64.
// A-frags are wave-private register loads (compiler-pipelined 1 iter ahead,
// 2 named reg sets). B stays LDS-staged (XOR swizzle, 0 conflicts), counted
// vmcnt(4) keeps next B-tile's 4 loads in flight. 32 KB LDS -> 2 blocks/CU.
template <int MODE>
__global__ __launch_bounds__(256, 2) void gemm_ad_kernel(
    const u16* __restrict__ A, const u16* __restrict__ Bt, float* __restrict__ C,
    int N, int K, int xlogn,
    const float* __restrict__ orig, const float* __restrict__ gains,
    u16* __restrict__ CbT) {
  __shared__ __attribute__((aligned(16))) u16 Bsb[2][128 * 64];  // 32 KB
  const int tid = threadIdx.x;
  const int l = tid & 63, w = tid >> 6;
  // XCD-rect swizzle over 512 blocks: 8 XCDs in (xm x xn) grid, 8x8 rect each.
  const int xc = blockIdx.x & 7, rblk = blockIdx.x >> 3;
  const int xn = xc & ((1 << xlogn) - 1), xm = xc >> xlogn;
  const int bm = xm * 8 + (rblk >> 3);
  const int bn = xn * 8 + (rblk & 7);
  const int nt = K >> 6;   // even

  // B staging: wave w, unit u covers rows (u*4+w)*8 .. +7 of the 128-row tile.
  // lane l: row +(l>>3), fetch global 16B-chunk ((l&7) ^ (l>>3)) of the 128B row
  // -> LDS[r][c] = G[r][c ^ (r&7)] (involution; reads apply same XOR).
  const int cs = (l & 7) ^ (l >> 3);
  const int rsub = l >> 3;
  const u16* bS[4]; int tO[4];
  #pragma unroll
  for (int u = 0; u < 4; ++u) {
    const int rg = (u * 4 + w) * 8 + rsub;
    bS[u] = Bt + (size_t)(bn * 128 + rg) * K + cs * 8;
    tO[u] = (u * 4 + w) * 512;
  }

#define STAGEB(buf, tt) do {                                               \
    const long so_ = (long)(tt) * 64;                                      \
    gload16(bS[0] + so_, (buf) + tO[0]); gload16(bS[1] + so_, (buf) + tO[1]); \
    gload16(bS[2] + so_, (buf) + tO[2]); gload16(bS[3] + so_, (buf) + tO[3]); \
  } while (0)

  const int wr = w >> 1, wc = w & 1;
  const int rA0 = wr * 64 + (l & 15);
  const int rB0 = wc * 64 + (l & 15);
  const int jk0 = (l >> 4) ^ (l & 7);        // swizzled chunk, k-half 0
  const int jk1 = ((l >> 4) + 4) ^ (l & 7);  // swizzled chunk, k-half 1

  // A direct-load base: lane covers row rA0 + mi*16, 16B chunk (l>>4) of K-tile.
  const u16* aBase = A + (size_t)(bm * 128 + rA0) * K + (l >> 4) * 8;

  f32x4 acc[4][4];
  #pragma unroll
  for (int i = 0; i < 4; ++i)
    #pragma unroll
    for (int j = 0; j < 4; ++j) acc[i][j] = (f32x4){0.f, 0.f, 0.f, 0.f};

  bf16x8 aE0[4], aE1[4], aO0[4], aO1[4], b0[4], b1[4];

  // prologue: A(0) -> aE; stage B(0), B(1)
  load_a(aBase, 0, K, aE0, aE1);
  STAGEB((u16*)Bsb[0], 0);
  STAGEB((u16*)Bsb[1], 1);
  VMWAIT(4);   // A(0) + B(0) landed; B(1)'s 4 loads in flight
  sbar();

  for (int t = 0; t < nt; t += 2) {
    const bool more = (t + 2) < nt;
    // ---- even tile t: buf0, aE; prefetch A(t+1) -> aO ----
    load_a(aBase, (long)(t + 1) * 64, K, aO0, aO1);
    read_b((const u16*)Bsb[0], rB0, jk0, jk1, b0, b1);
    do_mfma(aE0, aE1, b0, b1, acc);
    sbar();   // all waves done reading buf0
    if (more) { STAGEB((u16*)Bsb[0], t + 2); VMWAIT(4); }
    else      { VMWAIT(0); }
    sbar();
    // ---- odd tile t+1: buf1, aO; prefetch A(t+2) -> aE ----
    if (more) load_a(aBase, (long)(t + 2) * 64, K, aE0, aE1);
    read_b((const u16*)Bsb[1], rB0, jk0, jk1, b0, b1);
    do_mfma(aO0, aO1, b0, b1, acc);
    sbar();   // all waves done reading buf1
    if (more) { STAGEB((u16*)Bsb[1], t + 3); VMWAIT(4); }
    else      { VMWAIT(0); }
    sbar();
  }
#undef STAGEB

  // ---------------- epilogue ----------------
  const int rb = bm * 128 + wr * 64 + ((l >> 4) * 4);
  const int cb = bn * 128 + wc * 64 + (l & 15);
  #pragma unroll
  for (int mi = 0; mi < 4; ++mi) {
    const int row0 = rb + mi * 16;
    float gv[4] = {0.f, 0.f, 0.f, 0.f};
    if (MODE == 1) {
      #pragma unroll
      for (int j = 0; j < 4; ++j) gv[j] = 5.0f / (1.0f + expf(-gains[row0 + j]));
    }
    #pragma unroll
    for (int ni = 0; ni < 4; ++ni) {
      const int col = cb + ni * 16;
      f32x4 v = acc[mi][ni];
      if (MODE == 1) {
        float cpv[4];
        #pragma unroll
        for (int j = 0; j < 4; ++j) {
          float t = v[j] + orig[(size_t)(row0 + j) * N + col];
          cpv[j] = tanhf(t * gv[j]);
          C[(size_t)(row0 + j) * N + col] = cpv[j];
        }
        u16x4 o = { f2bf(cpv[0]), f2bf(cpv[1]), f2bf(cpv[2]), f2bf(cpv[3]) };
        *(u16x4*)(CbT + (size_t)col * 2048 + row0) = o;
      } else {
        #pragma unroll
        for (int j = 0; j < 4; ++j)
          C[(size_t)(row0 + j) * N + col] = v[j];
      }
    }
  }
}

extern "C" void kernel_launch(void* const* d_in, const int* in_sizes, int n_in,
                              void* d_out, int out_size, void* d_ws, size_t ws_size,
                              hipStream_t stream) {
  const float* cp     = (const float*)d_in[0];
  const float* w1     = (const float*)d_in[1];
  const float* w2     = (const float*)d_in[2];
  const float* audio  = (const float*)d_in[3];
  const float* decays = (const float*)d_in[4];
  const float* gains  = (const float*)d_in[5];

  float* out0 = (float*)d_out;                   // audio_out: [t][w] flat
  float* out1 = out0 + (size_t)2048 * 4096;      // cp_out: [c][t]

  char* ws = (char*)d_ws;
  u16*   w1b    = (u16*)(ws);                    //  8 MB
  u16*   w2b    = (u16*)(ws + 8388608);          //  8 MB
  u16*   audiob = (u16*)(ws + 16777216);         //  8 MB
  float* orig   = (float*)(ws + 25165824);       // 32 MB
  u16*   yT     = (u16*)(ws + 58720256);         // 16 MB
  u16*   x0t    = (u16*)(ws + 75497472);         // 16 MB
  u16*   cpbT   = x0t;                           // reuse after GEMM1
  float* Lbuf   = (float*)(ws + 75497472);       // overlap (dead between GEMM1/GEMM2)
  float* Cin    = (float*)(ws + 75497472 + 524288);

  cvt3_kernel<<<12288, 256, 0, stream>>>(w1, w2, audio, w1b);
  relu_t_kernel<<<2048, 256, 0, stream>>>(cp, x0t);

  // x = w1 @ relu(cp) -> orig[2048][4096]   (16bm x 32bn; XCD grid 2x4)
  gemm_ad_kernel<0><<<512, 256, 0, stream>>>(w1b, x0t, orig, 4096, 2048, 2,
                                             nullptr, nullptr, nullptr);
  // y = IIR(orig) -> yT[4096][2048] bf16
  iir_partial_kernel<<<1024, 128, 0, stream>>>(orig, decays, Lbuf);
  iir_carry_kernel<<<16, 128, 0, stream>>>(Lbuf, decays, Cin);
  iir_apply_kernel<<<1024, 128, 0, stream>>>(orig, decays, Cin, yT);
  // x2 = w2 @ y + orig; cp_out = tanh(x2*g) -> out1 f32, cpbT[t][c] bf16
  gemm_ad_kernel<1><<<512, 256, 0, stream>>>(w2b, yT, out1, 4096, 2048, 2,
                                             orig, gains, cpbT);
  // audio_out[t][w] = cpbT @ audiob^T   (32bm x 16bn; XCD grid 4x2)
  gemm_ad_kernel<0><<<512, 256, 0, stream>>>(cpbT, audiob, out0, 2048, 2048, 1,
                                             nullptr, nullptr, nullptr);
}

// Round 7
// 186.513 us; speedup vs baseline: 1.5809x; 1.5809x over previous
//
#include <hip/hip_runtime.h>
#include <math.h>

typedef __attribute__((ext_vector_type(8))) short bf16x8;
typedef __attribute__((ext_vector_type(8))) unsigned short u16x8;
typedef __attribute__((ext_vector_type(4))) unsigned short u16x4;
typedef __attribute__((ext_vector_type(4))) float f32x4;
typedef unsigned short u16;

__device__ __forceinline__ u16 f2bf(float f) {
  unsigned u = __builtin_bit_cast(unsigned, f);
  return (u16)((u + 0x7FFFu + ((u >> 16) & 1u)) >> 16);
}

__device__ __forceinline__ void gload16(const u16* g, u16* l) {
  __builtin_amdgcn_global_load_lds((const __attribute__((address_space(1))) void*)g,
                                   (__attribute__((address_space(3))) void*)l, 16, 0, 0);
}

__device__ __forceinline__ void sbar() {
  __builtin_amdgcn_sched_barrier(0);
  __builtin_amdgcn_s_barrier();
  __builtin_amdgcn_sched_barrier(0);
}

#define VMWAIT(n) asm volatile("s_waitcnt vmcnt(" #n ")" ::: "memory")
#define MFMA16(a, b, c) __builtin_amdgcn_mfma_f32_16x16x32_bf16((a), (b), (c), 0, 0, 0)

__device__ __forceinline__ float decay_of(float d) {
  return 1e-12f + 0.5f + 0.5f / (1.0f + expf(-d));
}

// ---------------- prep: 3x f32 -> bf16 (w1, w2, audio fused) ----------------
__global__ __launch_bounds__(256) void cvt3_kernel(const float* __restrict__ a,
                                                   const float* __restrict__ b,
                                                   const float* __restrict__ c,
                                                   u16* __restrict__ out) {
  const int i = blockIdx.x * 256 + threadIdx.x;   // i < 3 * 1048576 (float4 units)
  const float* src;
  int j = i;
  if (i < 1048576) { src = a; }
  else if (i < 2097152) { src = b; j = i - 1048576; }
  else { src = c; j = i - 2097152; }
  const float4 v = ((const float4*)src)[j];
  u16x4 o = { f2bf(v.x), f2bf(v.y), f2bf(v.z), f2bf(v.w) };
  ((u16x4*)out)[i] = o;
}

// ---------------- prep: relu(cp) transposed to [t][c] bf16 ----------------
__global__ __launch_bounds__(256) void relu_t_kernel(const float* __restrict__ cp,
                                                     u16* __restrict__ x0t) {
  const int cb = blockIdx.x & 31;
  const int tb = blockIdx.x >> 5;
  __shared__ __attribute__((aligned(16))) float tile[64][65];
  const int tid = threadIdx.x;
  const int r0 = tid >> 4, i4 = (tid & 15) * 4;
  #pragma unroll
  for (int rr = 0; rr < 64; rr += 16) {
    const float4 v = *(const float4*)(cp + (size_t)(cb * 64 + r0 + rr) * 4096 + tb * 64 + i4);
    tile[r0 + rr][i4 + 0] = fmaxf(v.x, 0.f);
    tile[r0 + rr][i4 + 1] = fmaxf(v.y, 0.f);
    tile[r0 + rr][i4 + 2] = fmaxf(v.z, 0.f);
    tile[r0 + rr][i4 + 3] = fmaxf(v.w, 0.f);
  }
  __syncthreads();
  #pragma unroll
  for (int it = 0; it < 2; ++it) {
    const int chunk = it * 256 + tid;
    const int i = chunk >> 3, rp = (chunk & 7) * 8;
    u16x8 o;
    #pragma unroll
    for (int q = 0; q < 8; ++q) o[q] = f2bf(tile[rp + q][i]);
    *(u16x8*)(x0t + (size_t)(tb * 64 + i) * 2048 + cb * 64 + rp) = o;
  }
}

// ---------------- IIR blocked scan ----------------
__global__ __launch_bounds__(128) void iir_partial_kernel(const float* __restrict__ x,
                                                          const float* __restrict__ decays,
                                                          float* __restrict__ L) {
  const int tid = threadIdx.x;
  const int cb = blockIdx.x & 15;
  const int ck = blockIdx.x >> 4;
  const int c0 = cb * 128, t0 = ck * 64;
  __shared__ __attribute__((aligned(16))) float xs[128][65];
  const float dd = decay_of(decays[c0 + tid]);
  #pragma unroll
  for (int it = 0; it < 16; ++it) {
    const int idx = it * 128 + tid;
    const int r = idx >> 4, iv = (idx & 15) * 4;
    const float4 v = *(const float4*)(x + (size_t)(c0 + r) * 4096 + t0 + iv);
    xs[r][iv + 0] = v.x; xs[r][iv + 1] = v.y; xs[r][iv + 2] = v.z; xs[r][iv + 3] = v.w;
  }
  __syncthreads();
  float yv = 0.0f;
  #pragma unroll
  for (int i = 0; i < 64; ++i) yv = dd * (xs[tid][i] + yv);
  L[ck * 2048 + c0 + tid] = yv;
}

__global__ __launch_bounds__(128) void iir_carry_kernel(const float* __restrict__ L,
                                                        const float* __restrict__ decays,
                                                        float* __restrict__ Cin) {
  const int c = blockIdx.x * 128 + threadIdx.x;
  const float dd = decay_of(decays[c]);
  float A = dd;
  #pragma unroll
  for (int p = 0; p < 6; ++p) A = A * A;   // dd^64
  float carry = 0.0f;
  for (int j = 0; j < 64; ++j) {
    Cin[j * 2048 + c] = carry;
    carry = L[j * 2048 + c] + A * carry;
  }
}

__global__ __launch_bounds__(128) void iir_apply_kernel(const float* __restrict__ x,
                                                        const float* __restrict__ decays,
                                                        const float* __restrict__ Cin,
                                                        u16* __restrict__ yT) {
  const int tid = threadIdx.x;
  const int cb = blockIdx.x & 15;
  const int ck = blockIdx.x >> 4;
  const int c0 = cb * 128, t0 = ck * 64;
  __shared__ __attribute__((aligned(16))) float xs[128][65];
  __shared__ __attribute__((aligned(16))) u16 ys[64][136];
  const float dd = decay_of(decays[c0 + tid]);
  const float carry = Cin[ck * 2048 + c0 + tid];
  #pragma unroll
  for (int it = 0; it < 16; ++it) {
    const int idx = it * 128 + tid;
    const int r = idx >> 4, iv = (idx & 15) * 4;
    const float4 v = *(const float4*)(x + (size_t)(c0 + r) * 4096 + t0 + iv);
    xs[r][iv + 0] = v.x; xs[r][iv + 1] = v.y; xs[r][iv + 2] = v.z; xs[r][iv + 3] = v.w;
  }
  __syncthreads();
  float yv = carry;
  #pragma unroll
  for (int i = 0; i < 64; ++i) {
    yv = dd * (xs[tid][i] + yv);
    ys[i][tid] = f2bf(yv);
  }
  __syncthreads();
  #pragma unroll
  for (int it = 0; it < 8; ++it) {
    const int chunk = it * 128 + tid;
    const int i = chunk >> 4, cpv = (chunk & 15) * 8;
    u16x8 v = *(const u16x8*)&ys[i][cpv];
    *(u16x8*)(yT + (size_t)(t0 + i) * 2048 + c0 + cpv) = v;
  }
}

// ---------------- GEMM helpers ----------------
__device__ __forceinline__ void read_frag(const u16* Ac, const u16* Bc,
                                          int rA0, int rB0, int jk,
                                          bf16x8 (&a)[4], bf16x8 (&b)[4]) {
  #pragma unroll
  for (int i = 0; i < 4; ++i)
    a[i] = *(const bf16x8*)(Ac + (rA0 + i * 16) * 64 + jk * 8);
  #pragma unroll
  for (int i = 0; i < 4; ++i)
    b[i] = *(const bf16x8*)(Bc + (rB0 + i * 16) * 64 + jk * 8);
}

__device__ __forceinline__ void mfma16x(const bf16x8 (&a)[4], const bf16x8 (&b)[4],
                                        f32x4 (&acc)[4][4]) {
  __builtin_amdgcn_s_setprio(1);
  #pragma unroll
  for (int mi = 0; mi < 4; ++mi)
    #pragma unroll
    for (int ni = 0; ni < 4; ++ni)
      acc[mi][ni] = MFMA16(a[mi], b[ni], acc[mi][ni]);
  __builtin_amdgcn_s_setprio(0);
}

// ---------------- GEMM: 128x128 tile, BK=64, double-buffer, pipelined, 2 blocks/CU ----------------
// C[M][N] = A[M][K] @ Bt[N][K]^T. 256 thr = 4 waves (2M x 2N), per-wave 64x64.
// One barrier per K-tile. Per tile h: read k1 frags (fly under k0 MFMA),
// MFMA k0, MFMA k1, vmcnt(0) [tile h+1 landed, staged 1 iter ago], barrier,
// stage tile h+2 into buf[h&1], tail-read k0 frags of tile h+1 (other buffer).
template <int MODE>
__global__ __launch_bounds__(256, 2) void gemm_pl_kernel(
    const u16* __restrict__ A, const u16* __restrict__ Bt, float* __restrict__ C,
    int N, int K, int xlogn,
    const float* __restrict__ orig, const float* __restrict__ gains,
    u16* __restrict__ CbT) {
  __shared__ __attribute__((aligned(16))) u16 Asb[2][128 * 64];  // 32 KB
  __shared__ __attribute__((aligned(16))) u16 Bsb[2][128 * 64];  // 32 KB
  const int tid = threadIdx.x;
  const int l = tid & 63, w = tid >> 6;
  // XCD-rect swizzle over 512 blocks: 8 XCDs in (xm x xn) grid, 8x8 rect each.
  const int xc = blockIdx.x & 7, rblk = blockIdx.x >> 3;
  const int xn = xc & ((1 << xlogn) - 1), xm = xc >> xlogn;
  const int bm = xm * 8 + (rblk >> 3);
  const int bn = xn * 8 + (rblk & 7);
  const int nt = K >> 6;   // 32

  // staging: wave w, unit u covers rows (u*4+w)*8 .. +7 of the 128-row tile.
  // lane l: row +(l>>3), fetch global 16B-chunk ((l&7) ^ (l>>3)) of the 128B row
  // -> LDS[r][c] = G[r][c ^ (r&7)] (involution; reads apply same XOR).
  const int cs = (l & 7) ^ (l >> 3);
  const int rsub = l >> 3;
  const u16* aS[4]; const u16* bS[4]; int tO[4];
  #pragma unroll
  for (int u = 0; u < 4; ++u) {
    const int rg = (u * 4 + w) * 8 + rsub;
    aS[u] = A  + (size_t)(bm * 128 + rg) * K + cs * 8;
    bS[u] = Bt + (size_t)(bn * 128 + rg) * K + cs * 8;
    tO[u] = (u * 4 + w) * 512;
  }

#define STAGE(bufA, bufB, tt) do {                                        \
    const long so_ = (long)(tt) * 64;                                     \
    gload16(aS[0] + so_, (bufA) + tO[0]); gload16(aS[1] + so_, (bufA) + tO[1]); \
    gload16(aS[2] + so_, (bufA) + tO[2]); gload16(aS[3] + so_, (bufA) + tO[3]); \
    gload16(bS[0] + so_, (bufB) + tO[0]); gload16(bS[1] + so_, (bufB) + tO[1]); \
    gload16(bS[2] + so_, (bufB) + tO[2]); gload16(bS[3] + so_, (bufB) + tO[3]); \
  } while (0)

  // prologue: tiles 0 and 1
  STAGE((u16*)Asb[0], (u16*)Bsb[0], 0);
  STAGE((u16*)Asb[1], (u16*)Bsb[1], 1);

  f32x4 acc[4][4];
  #pragma unroll
  for (int i = 0; i < 4; ++i)
    #pragma unroll
    for (int j = 0; j < 4; ++j) acc[i][j] = (f32x4){0.f, 0.f, 0.f, 0.f};

  const int wr = w >> 1, wc = w & 1;
  const int rA0 = wr * 64 + (l & 15);
  const int rB0 = wc * 64 + (l & 15);
  const int jk0 = (l >> 4) ^ (l & 7);        // swizzled chunk, k-half 0
  const int jk1 = ((l >> 4) + 4) ^ (l & 7);  // swizzled chunk, k-half 1

  bf16x8 pa[4], pb[4], qa[4], qb[4];

  VMWAIT(8);   // tile 0 landed (tile 1's 8 loads in flight)
  sbar();
  read_frag((const u16*)Asb[0], (const u16*)Bsb[0], rA0, rB0, jk0, pa, pb);

  for (int h = 0; h < nt; ++h) {
    const u16* Ac = (const u16*)Asb[0] + (h & 1) * 8192;
    const u16* Bc = (const u16*)Bsb[0] + (h & 1) * 8192;
    u16* Anx = (u16*)Asb[0] + (h & 1) * 8192;
    u16* Bnx = (u16*)Bsb[0] + (h & 1) * 8192;
    const u16* An1 = (const u16*)Asb[0] + ((h + 1) & 1) * 8192;
    const u16* Bn1 = (const u16*)Bsb[0] + ((h + 1) & 1) * 8192;

    // k1 reads fly under k0 MFMA
    read_frag(Ac, Bc, rA0, rB0, jk1, qa, qb);
    mfma16x(pa, pb, acc);        // pa ready (read last iteration's tail)
    mfma16x(qa, qb, acc);        // compiler lgkmcnt gates qa/qb
    VMWAIT(0);                   // tile h+1 landed (staged one iteration ago)
    sbar();                      // block-wide: buf[h&1] free, buf[(h+1)&1] valid
    if (h + 2 < nt) STAGE(Anx, Bnx, h + 2);
    if (h + 1 < nt) read_frag(An1, Bn1, rA0, rB0, jk0, pa, pb);
  }
#undef STAGE

  // ---------------- epilogue ----------------
  const int rb = bm * 128 + wr * 64 + ((l >> 4) * 4);
  const int cb = bn * 128 + wc * 64 + (l & 15);
  #pragma unroll
  for (int mi = 0; mi < 4; ++mi) {
    const int row0 = rb + mi * 16;
    float gv[4] = {0.f, 0.f, 0.f, 0.f};
    if (MODE == 1) {
      #pragma unroll
      for (int j = 0; j < 4; ++j) gv[j] = 5.0f / (1.0f + expf(-gains[row0 + j]));
    }
    #pragma unroll
    for (int ni = 0; ni < 4; ++ni) {
      const int col = cb + ni * 16;
      f32x4 v = acc[mi][ni];
      if (MODE == 1) {
        float cpv[4];
        #pragma unroll
        for (int j = 0; j < 4; ++j) {
          float t = v[j] + orig[(size_t)(row0 + j) * N + col];
          cpv[j] = tanhf(t * gv[j]);
          C[(size_t)(row0 + j) * N + col] = cpv[j];
        }
        u16x4 o = { f2bf(cpv[0]), f2bf(cpv[1]), f2bf(cpv[2]), f2bf(cpv[3]) };
        *(u16x4*)(CbT + (size_t)col * 2048 + row0) = o;
      } else {
        #pragma unroll
        for (int j = 0; j < 4; ++j)
          C[(size_t)(row0 + j) * N + col] = v[j];
      }
    }
  }
}

extern "C" void kernel_launch(void* const* d_in, const int* in_sizes, int n_in,
                              void* d_out, int out_size, void* d_ws, size_t ws_size,
                              hipStream_t stream) {
  const float* cp     = (const float*)d_in[0];
  const float* w1     = (const float*)d_in[1];
  const float* w2     = (const float*)d_in[2];
  const float* audio  = (const float*)d_in[3];
  const float* decays = (const float*)d_in[4];
  const float* gains  = (const float*)d_in[5];

  float* out0 = (float*)d_out;                   // audio_out: [t][w] flat
  float* out1 = out0 + (size_t)2048 * 4096;      // cp_out: [c][t]

  char* ws = (char*)d_ws;
  u16*   w1b    = (u16*)(ws);                    //  8 MB
  u16*   w2b    = (u16*)(ws + 8388608);          //  8 MB
  u16*   audiob = (u16*)(ws + 16777216);         //  8 MB
  float* orig   = (float*)(ws + 25165824);       // 32 MB
  u16*   yT     = (u16*)(ws + 58720256);         // 16 MB
  u16*   x0t    = (u16*)(ws + 75497472);         // 16 MB
  u16*   cpbT   = x0t;                           // reuse after GEMM1
  float* Lbuf   = (float*)(ws + 75497472);       // overlap (dead between GEMM1/GEMM2)
  float* Cin    = (float*)(ws + 75497472 + 524288);

  cvt3_kernel<<<12288, 256, 0, stream>>>(w1, w2, audio, w1b);
  relu_t_kernel<<<2048, 256, 0, stream>>>(cp, x0t);

  // x = w1 @ relu(cp) -> orig[2048][4096]   (16bm x 32bn; XCD grid 2x4)
  gemm_pl_kernel<0><<<512, 256, 0, stream>>>(w1b, x0t, orig, 4096, 2048, 2,
                                             nullptr, nullptr, nullptr);
  // y = IIR(orig) -> yT[4096][2048] bf16
  iir_partial_kernel<<<1024, 128, 0, stream>>>(orig, decays, Lbuf);
  iir_carry_kernel<<<16, 128, 0, stream>>>(Lbuf, decays, Cin);
  iir_apply_kernel<<<1024, 128, 0, stream>>>(orig, decays, Cin, yT);
  // x2 = w2 @ y + orig; cp_out = tanh(x2*g) -> out1 f32, cpbT[t][c] bf16
  gemm_pl_kernel<1><<<512, 256, 0, stream>>>(w2b, yT, out1, 4096, 2048, 2,
                                             orig, gains, cpbT);
  // audio_out[t][w] = cpbT @ audiob^T   (32bm x 16bn; XCD grid 4x2)
  gemm_pl_kernel<0><<<512, 256, 0, stream>>>(cpbT, audiob, out0, 2048, 2048, 1,
                                             nullptr, nullptr, nullptr);
}